// Round 2
// baseline (11812.524 us; speedup 1.0000x reference)
//
#include <hip/hip_runtime.h>
#include <hip/hip_cooperative_groups.h>
#include <math.h>

namespace cg = cooperative_groups;

#define Tsz 512
#define NBLK 256
#define NTHR 512

// LDS pitches (shorts): dword pitch ≡ 4 (mod 32), 16B-aligned — empirical optimum for
// the MFMA fragment b128 pattern (R5/R8: 2.4e8 conflicts; odd-dw: 4.4e8; ≡0: 1.1e9).
#define PB0 328   // B h0|x rows (320 used)  164 dw
#define PB1 264   // B h1 rows  (256 used)   132 dw
#define B1B 5248  // 16*PB0

typedef short short8  __attribute__((ext_vector_type(8)));
typedef short short4v __attribute__((ext_vector_type(4)));
typedef float float4v __attribute__((ext_vector_type(4)));

#define MFMA16(a, b, c) __builtin_amdgcn_mfma_f32_16x16x32_bf16((a), (b), (c), 0, 0, 0)
#define LOADX(p) __hip_atomic_load((p), __ATOMIC_RELAXED, __HIP_MEMORY_SCOPE_AGENT)
#define STOREX(p, v) __hip_atomic_store((p), (v), __ATOMIC_RELAXED, __HIP_MEMORY_SCOPE_AGENT)

__device__ __forceinline__ float sigm(float x) { return 1.0f / (1.0f + __expf(-x)); }
__device__ __forceinline__ float tanh_fast(float x) { return 2.0f / (1.0f + __expf(-2.0f * x)) - 1.0f; }

// fp32 -> bf16 hi (x) + bf16 lo (y), RNE both
__device__ __forceinline__ short2 split1(float f) {
    unsigned u = __float_as_uint(f);
    unsigned r = u + 0x7FFFu + ((u >> 16) & 1u);
    short h = (short)(r >> 16);
    float hf = __uint_as_float(r & 0xFFFF0000u);
    float d  = f - hf;
    unsigned u2 = __float_as_uint(d);
    unsigned r2 = u2 + 0x7FFFu + ((u2 >> 16) & 1u);
    return make_short2(h, (short)(r2 >> 16));
}

// Weight-stationary 2-layer LSTM, bf16-split-3 MFMA, ONE pass per superstep.
// 256 blocks = 16 row-slices (16 cols) x 16 batch-slices (16 batches).
// M=128 rows (L0 rows 0..63 = gate*16+col, L1 rows 64..127), N=16 batches.
// 8 waves = 8 16x16 tiles, FULL K per wave (L0: K=320 h0|x, L1: K=512 h0|h1).
// Sync: 16 distributed per-block flag words in one 64B line per bs-group.
// Producer: release-fence + own-flag store after S3 (parallel, no RMW chain).
// Consumer: relaxed 16-lane line spin + acquire-fence before h loads.
__global__ __launch_bounds__(NTHR, 1)
void lstm2_mfma(const float* __restrict__ x,
                const float* __restrict__ Wih0, const float* __restrict__ Whh0,
                const float* __restrict__ bih0, const float* __restrict__ bhh0,
                const float* __restrict__ Wih1, const float* __restrict__ Whh1,
                const float* __restrict__ bih1, const float* __restrict__ bhh1,
                const float* __restrict__ Wf,   const float* __restrict__ bf,
                float* __restrict__ out, float* __restrict__ ws)
{
    cg::grid_group grid = cg::this_grid();
    const int tid = threadIdx.x;
    const int rs  = blockIdx.x >> 4;   // row-slice: cols [rs*16, rs*16+16)
    const int bs  = blockIdx.x & 15;   // batch-slice: batches [bs*16, bs*16+16)
    const int bbase = bs * 16;

    __shared__ short Bh[2][9472];      // 37.9 KB (h0|x: 16*PB0, h1: 16*PB1)
    __shared__ float zf[128][17];      // 8.7 KB

    unsigned* h0u = (unsigned*)ws;             // [2 parity][256 batch][256 col] packed
    unsigned* h1u = (unsigned*)ws + 2 * 256 * 256;
    unsigned* syn = (unsigned*)ws + 4 * 256 * 256;
    // flags: syn[bs*256 + rs], 16 words = one 64B line per bs-group, lines 1KB apart

    // ---- init ----
    for (int i = blockIdx.x * NTHR + tid; i < 4 * 256 * 256; i += NBLK * NTHR)
        ((unsigned*)ws)[i] = 0u;
    if (tid == 0) STOREX(&syn[bs * 256 + rs], 0u);
    if (rs == 0 && tid < 16) out[bbase + tid] = bf[0];

    // ---- mfma lane decode ----
    const int w = tid >> 6, lane = tid & 63;
    const int quad = lane >> 4, n16 = lane & 15;
    const int bBase0 = n16 * PB0 + quad * 8;
    const int bBase1 = B1B + n16 * PB1 + quad * 8;

    // ---- weight A-fragments -> registers (full K per wave) ----
    // Wave w<4: L0 tile rows w*16..+16 (within-layer row r = w*16+n16).
    // Wave w>=4: L1 tile rows (w-4)*16..+16.
    short8 wfh[16], wfl[16];
    {
        const int r = (w & 3) * 16 + n16;            // within-layer row 0..63
        const int g = r >> 4, cc = r & 15;
        const size_t grow = (size_t)(g * 256 + rs * 16 + cc);
        const int nkc = (w < 4) ? 10 : 16;
        #pragma unroll
        for (int kc = 0; kc < 16; ++kc) {
            if (kc < nkc) {
                const int k = kc * 32 + quad * 8;
                const float* src;
                if (w < 4)                           // L0: k<256 -> Whh0, else Wih0
                    src = (k < 256) ? &Whh0[grow * 256 + k] : &Wih0[grow * 64 + (k - 256)];
                else                                 // L1: k<256 -> Wih1 (vs h0), else Whh1 (vs h1)
                    src = (k < 256) ? &Wih1[grow * 256 + k] : &Whh1[grow * 256 + (k - 256)];
                float4 f0 = *(const float4*)src;
                float4 f1 = *(const float4*)(src + 4);
                short8 hi, lo; short2 t;
                t = split1(f0.x); hi[0] = t.x; lo[0] = t.y;
                t = split1(f0.y); hi[1] = t.x; lo[1] = t.y;
                t = split1(f0.z); hi[2] = t.x; lo[2] = t.y;
                t = split1(f0.w); hi[3] = t.x; lo[3] = t.y;
                t = split1(f1.x); hi[4] = t.x; lo[4] = t.y;
                t = split1(f1.y); hi[5] = t.x; lo[5] = t.y;
                t = split1(f1.z); hi[6] = t.x; lo[6] = t.y;
                t = split1(f1.w); hi[7] = t.x; lo[7] = t.y;
                wfh[kc] = hi; wfl[kc] = lo;
            }
        }
    }

    // ---- updater decode: all 512 threads, cell (layer ul, col ucc, batch ub) ----
    const int ul = tid >> 8, ub = (tid >> 4) & 15, ucc = tid & 15;
    const int ucol = rs * 16 + ucc;
    float ubias[4];
    {
        const float* bi = ul ? bih1 : bih0;
        const float* bh = ul ? bhh1 : bhh0;
        #pragma unroll
        for (int g = 0; g < 4; ++g) ubias[g] = bi[g * 256 + ucol] + bh[g * 256 + ucol];
    }
    float cst = 0.f, h1last = 0.f;

    // staging decode
    const int sn = tid >> 5, sk = (tid & 31) * 8;
    const int xn = tid >> 4, xd4 = (tid & 15) * 4;

    grid.sync();   // init visible device-wide

    float4 xpre;
    if (tid < 256)
        xpre = *(const float4*)&x[((size_t)(bbase + xn) * Tsz + 0) * 64 + xd4];

    for (int s = 0; s <= Tsz; ++s) {
        const int rp = (s + 1) & 1;   // parity of h0[s-1]
        const int rq = s & 1;         // parity of h1[s-2]

        // ---- wait for superstep s-1 of this bs-group: 16-lane line poll ----
        if (s > 0) {
            const unsigned* fl = &syn[bs * 256 + (lane & 15)];
            while (!__all((int)(LOADX(fl) >= (unsigned)s)))
                __builtin_amdgcn_s_sleep(1);
            __builtin_amdgcn_fence(__ATOMIC_ACQUIRE, "agent");
        }

        // ---- stage h0[s-1], h1[s-2] (packed-uint load + v_perm unpack), x[s] ----
        {
            const unsigned* q0 = &h0u[((size_t)(rp * 256) + bbase + sn) * 256 + sk];
            const unsigned* q1 = &h1u[((size_t)(rq * 256) + bbase + sn) * 256 + sk];
            unsigned a[8], b[8];
            #pragma unroll
            for (int i = 0; i < 8; ++i) a[i] = LOADX(q0 + i);
            #pragma unroll
            for (int i = 0; i < 8; ++i) b[i] = LOADX(q1 + i);
            uint4 hi4, lo4;
            hi4.x = __builtin_amdgcn_perm(a[1], a[0], 0x07060302u);
            hi4.y = __builtin_amdgcn_perm(a[3], a[2], 0x07060302u);
            hi4.z = __builtin_amdgcn_perm(a[5], a[4], 0x07060302u);
            hi4.w = __builtin_amdgcn_perm(a[7], a[6], 0x07060302u);
            lo4.x = __builtin_amdgcn_perm(a[1], a[0], 0x05040100u);
            lo4.y = __builtin_amdgcn_perm(a[3], a[2], 0x05040100u);
            lo4.z = __builtin_amdgcn_perm(a[5], a[4], 0x05040100u);
            lo4.w = __builtin_amdgcn_perm(a[7], a[6], 0x05040100u);
            *(uint4*)&Bh[0][sn * PB0 + sk] = hi4;
            *(uint4*)&Bh[1][sn * PB0 + sk] = lo4;
            hi4.x = __builtin_amdgcn_perm(b[1], b[0], 0x07060302u);
            hi4.y = __builtin_amdgcn_perm(b[3], b[2], 0x07060302u);
            hi4.z = __builtin_amdgcn_perm(b[5], b[4], 0x07060302u);
            hi4.w = __builtin_amdgcn_perm(b[7], b[6], 0x07060302u);
            lo4.x = __builtin_amdgcn_perm(b[1], b[0], 0x05040100u);
            lo4.y = __builtin_amdgcn_perm(b[3], b[2], 0x05040100u);
            lo4.z = __builtin_amdgcn_perm(b[5], b[4], 0x05040100u);
            lo4.w = __builtin_amdgcn_perm(b[7], b[6], 0x05040100u);
            *(uint4*)&Bh[0][B1B + sn * PB1 + sk] = hi4;
            *(uint4*)&Bh[1][B1B + sn * PB1 + sk] = lo4;
        }
        if (s < Tsz && tid < 256) {
            float4 xv = xpre;
            short4v xh, xl; short2 t;
            t = split1(xv.x); xh[0] = t.x; xl[0] = t.y;
            t = split1(xv.y); xh[1] = t.x; xl[1] = t.y;
            t = split1(xv.z); xh[2] = t.x; xl[2] = t.y;
            t = split1(xv.w); xh[3] = t.x; xl[3] = t.y;
            *(short4v*)&Bh[0][xn * PB0 + 256 + xd4] = xh;
            *(short4v*)&Bh[1][xn * PB0 + 256 + xd4] = xl;
        }
        __syncthreads();   // S1: Bh staged

        // x prefetch for next superstep (drains naturally before use)
        if (tid < 256 && s + 1 < Tsz)
            xpre = *(const float4*)&x[((size_t)(bbase + xn) * Tsz + (s + 1)) * 64 + xd4];

        // ---- MFMA: full-K tile per wave, register A-frags, 3 independent
        //      accumulator chains (hi*hi / hi*lo / lo*hi) to cut dep latency ----
        float4v a0 = {0.f, 0.f, 0.f, 0.f};
        float4v a1 = {0.f, 0.f, 0.f, 0.f};
        float4v a2 = {0.f, 0.f, 0.f, 0.f};
        if (w < 4) {                         // L0: K=320 over h0|x
            #pragma unroll
            for (int kc = 0; kc < 10; ++kc) {
                const int bo = bBase0 + kc * 32;
                short8 bh2 = *(const short8*)&Bh[0][bo];
                short8 bl2 = *(const short8*)&Bh[1][bo];
                a0 = MFMA16(wfh[kc], bh2, a0);
                a1 = MFMA16(wfh[kc], bl2, a1);
                a2 = MFMA16(wfl[kc], bh2, a2);
            }
        } else {                             // L1: K=512 (h0 then h1)
            #pragma unroll
            for (int kc = 0; kc < 8; ++kc) {
                const int bo = bBase0 + kc * 32;
                short8 bh2 = *(const short8*)&Bh[0][bo];
                short8 bl2 = *(const short8*)&Bh[1][bo];
                a0 = MFMA16(wfh[kc], bh2, a0);
                a1 = MFMA16(wfh[kc], bl2, a1);
                a2 = MFMA16(wfl[kc], bh2, a2);
            }
            #pragma unroll
            for (int kc = 8; kc < 16; ++kc) {
                const int bo = bBase1 + (kc - 8) * 32;
                short8 bh2 = *(const short8*)&Bh[0][bo];
                short8 bl2 = *(const short8*)&Bh[1][bo];
                a0 = MFMA16(wfh[kc], bh2, a0);
                a1 = MFMA16(wfh[kc], bl2, a1);
                a2 = MFMA16(wfl[kc], bh2, a2);
            }
        }
        float4v acc = (a0 + a1) + a2;
        #pragma unroll
        for (int r = 0; r < 4; ++r)
            zf[w * 16 + quad * 4 + r][n16] = acc[r];
        __syncthreads();   // S2: zf complete

        // ---- cell update (all 512 threads own one cell) ----
        {
            const bool active = ul ? (s >= 1) : (s < Tsz);
            if (active) {
                const int mb = ul * 64 + ucc;
                float z0 = zf[mb +  0][ub] + ubias[0];
                float z1 = zf[mb + 16][ub] + ubias[1];
                float z2 = zf[mb + 32][ub] + ubias[2];
                float z3 = zf[mb + 48][ub] + ubias[3];
                float ii = sigm(z0), ff = sigm(z1);
                float gg = tanh_fast(z2), oo = sigm(z3);
                float c = ff * cst + ii * gg; cst = c;
                float hval = oo * tanh_fast(c);
                short2 hl = split1(hval);
                unsigned pk = ((unsigned)(unsigned short)hl.x << 16) |
                              (unsigned)(unsigned short)hl.y;
                if (ul) {
                    h1last = hval;
                    STOREX(&h1u[((size_t)(((s + 1) & 1) * 256) + bbase + ub) * 256 + ucol], pk);
                } else {
                    STOREX(&h0u[((size_t)((s & 1) * 256) + bbase + ub) * 256 + ucol], pk);
                }
            }
        }

        // ---- drain (S3), then publish this block's arrival: release-fence +
        //      one parallel store to our own flag word (no RMW chain) ----
        __syncthreads();   // S3: per-wave vmcnt drained at barrier -> h stores visible
        if (tid == 0) {
            __builtin_amdgcn_fence(__ATOMIC_RELEASE, "agent");
            STOREX(&syn[bs * 256 + rs], (unsigned)(s + 1));
        }
    }

    // ---- epilogue: out[b] += sum_cols h1_final * Wf ----
    if (ul == 1) {
        atomicAdd(&out[bbase + ub], h1last * Wf[ucol]);
    }
}

extern "C" void kernel_launch(void* const* d_in, const int* in_sizes, int n_in,
                              void* d_out, int out_size, void* d_ws, size_t ws_size,
                              hipStream_t stream) {
    const float* x    = (const float*)d_in[0];
    const float* Wih0 = (const float*)d_in[1];
    const float* Whh0 = (const float*)d_in[2];
    const float* bih0 = (const float*)d_in[3];
    const float* bhh0 = (const float*)d_in[4];
    const float* Wih1 = (const float*)d_in[5];
    const float* Whh1 = (const float*)d_in[6];
    const float* bih1 = (const float*)d_in[7];
    const float* bhh1 = (const float*)d_in[8];
    const float* Wf   = (const float*)d_in[9];
    const float* bf   = (const float*)d_in[10];
    float* out = (float*)d_out;
    float* ws  = (float*)d_ws;   // 1 MB packed h buffers + 32 KB sync area

    void* args[] = {
        (void*)&x, (void*)&Wih0, (void*)&Whh0, (void*)&bih0, (void*)&bhh0,
        (void*)&Wih1, (void*)&Whh1, (void*)&bih1, (void*)&bhh1,
        (void*)&Wf, (void*)&bf, (void*)&out, (void*)&ws
    };
    hipLaunchCooperativeKernel((void*)lstm2_mfma, dim3(NBLK), dim3(NTHR),
                               args, 0, stream);
}

// Round 3
// 3574.900 us; speedup vs baseline: 3.3043x; 3.3043x over previous
//
#include <hip/hip_runtime.h>
#include <hip/hip_cooperative_groups.h>
#include <math.h>

namespace cg = cooperative_groups;

#define Tsz 512
#define NBLK 256
#define NTHR 512

// LDS pitches (shorts): dword pitch ≡ 4 (mod 32), 16B-aligned — empirical optimum for
// the MFMA fragment b128 pattern (R5/R8: 2.4e8 conflicts; odd-dw: 4.4e8; ≡0: 1.1e9).
#define PB0 328   // B h0|x rows (320 used)  164 dw
#define PB1 264   // B h1 rows  (256 used)   132 dw
#define B1B 5248  // 16*PB0

typedef short short8  __attribute__((ext_vector_type(8)));
typedef short short4v __attribute__((ext_vector_type(4)));
typedef float float4v __attribute__((ext_vector_type(4)));

#define MFMA16(a, b, c) __builtin_amdgcn_mfma_f32_16x16x32_bf16((a), (b), (c), 0, 0, 0)
#define LOADX(p) __hip_atomic_load((p), __ATOMIC_RELAXED, __HIP_MEMORY_SCOPE_AGENT)
#define STOREX(p, v) __hip_atomic_store((p), (v), __ATOMIC_RELAXED, __HIP_MEMORY_SCOPE_AGENT)

__device__ __forceinline__ float sigm(float x) { return 1.0f / (1.0f + __expf(-x)); }
__device__ __forceinline__ float tanh_fast(float x) { return 2.0f / (1.0f + __expf(-2.0f * x)) - 1.0f; }

// fp32 -> bf16 hi (x) + bf16 lo (y), RNE both
__device__ __forceinline__ short2 split1(float f) {
    unsigned u = __float_as_uint(f);
    unsigned r = u + 0x7FFFu + ((u >> 16) & 1u);
    short h = (short)(r >> 16);
    float hf = __uint_as_float(r & 0xFFFF0000u);
    float d  = f - hf;
    unsigned u2 = __float_as_uint(d);
    unsigned r2 = u2 + 0x7FFFu + ((u2 >> 16) & 1u);
    return make_short2(h, (short)(r2 >> 16));
}

// Weight-stationary 2-layer LSTM, bf16-split-3 MFMA, ONE pass per superstep.
// 256 blocks = 16 row-slices (16 cols) x 16 batch-slices (16 batches).
// M=128 rows (L0 rows 0..63 = gate*16+col, L1 rows 64..127), N=16 batches.
// 8 waves = 8 16x16 tiles, FULL K per wave (L0: K=320 h0|x, L1: K=512 h0|h1).
//
// Sync per bs-group (relay scheme, no fences, no RMW chain):
//   arrival line P: syn[bs*256 + rs], 16 words = one 64B line. Each block's
//     tid0 stores its own word after S3 (parallel stores; P is read by ONLY
//     the relay wave -> stores are never starved by poll floods).
//   relay: wave 0 of the rs==0 block tight-polls P (16 lanes + __all), then
//     publishes epoch F = syn[4096 + bs*256] (separate line, ONE store/step).
//   consumers: wave 0 polls F (s_sleep); S0 barrier releases waves 1..7.
// Ordering = baseline-strength: h-stores drain at S3 (vmcnt0) before the P
// store; F follows all P through L2; consumers load h only after seeing F.
__global__ __launch_bounds__(NTHR, 1)
void lstm2_mfma(const float* __restrict__ x,
                const float* __restrict__ Wih0, const float* __restrict__ Whh0,
                const float* __restrict__ bih0, const float* __restrict__ bhh0,
                const float* __restrict__ Wih1, const float* __restrict__ Whh1,
                const float* __restrict__ bih1, const float* __restrict__ bhh1,
                const float* __restrict__ Wf,   const float* __restrict__ bf,
                float* __restrict__ out, float* __restrict__ ws)
{
    cg::grid_group grid = cg::this_grid();
    const int tid = threadIdx.x;
    const int rs  = blockIdx.x >> 4;   // row-slice: cols [rs*16, rs*16+16)
    const int bs  = blockIdx.x & 15;   // batch-slice: batches [bs*16, bs*16+16)
    const int bbase = bs * 16;

    __shared__ short Bh[2][9472];      // 37.9 KB (h0|x: 16*PB0, h1: 16*PB1)
    __shared__ float zf[128][17];      // 8.7 KB

    unsigned* h0u = (unsigned*)ws;             // [2 parity][256 batch][256 col] packed
    unsigned* h1u = (unsigned*)ws + 2 * 256 * 256;
    unsigned* syn = (unsigned*)ws + 4 * 256 * 256;
    // P line: syn[bs*256 + rs] (16 words); F word: syn[4096 + bs*256]

    // ---- init ----
    for (int i = blockIdx.x * NTHR + tid; i < 4 * 256 * 256; i += NBLK * NTHR)
        ((unsigned*)ws)[i] = 0u;
    if (tid == 0) STOREX(&syn[bs * 256 + rs], 0u);
    if (rs == 0 && tid == 0) STOREX(&syn[4096 + bs * 256], 0u);
    if (rs == 0 && tid < 16) out[bbase + tid] = bf[0];

    // ---- mfma lane decode ----
    const int w = tid >> 6, lane = tid & 63;
    const int quad = lane >> 4, n16 = lane & 15;
    const int bBase0 = n16 * PB0 + quad * 8;
    const int bBase1 = B1B + n16 * PB1 + quad * 8;

    // ---- weight A-fragments -> registers (full K per wave) ----
    // Wave w<4: L0 tile rows w*16..+16 (within-layer row r = w*16+n16).
    // Wave w>=4: L1 tile rows (w-4)*16..+16.
    short8 wfh[16], wfl[16];
    {
        const int r = (w & 3) * 16 + n16;            // within-layer row 0..63
        const int g = r >> 4, cc = r & 15;
        const size_t grow = (size_t)(g * 256 + rs * 16 + cc);
        const int nkc = (w < 4) ? 10 : 16;
        #pragma unroll
        for (int kc = 0; kc < 16; ++kc) {
            if (kc < nkc) {
                const int k = kc * 32 + quad * 8;
                const float* src;
                if (w < 4)                           // L0: k<256 -> Whh0, else Wih0
                    src = (k < 256) ? &Whh0[grow * 256 + k] : &Wih0[grow * 64 + (k - 256)];
                else                                 // L1: k<256 -> Wih1 (vs h0), else Whh1 (vs h1)
                    src = (k < 256) ? &Wih1[grow * 256 + k] : &Whh1[grow * 256 + (k - 256)];
                float4 f0 = *(const float4*)src;
                float4 f1 = *(const float4*)(src + 4);
                short8 hi, lo; short2 t;
                t = split1(f0.x); hi[0] = t.x; lo[0] = t.y;
                t = split1(f0.y); hi[1] = t.x; lo[1] = t.y;
                t = split1(f0.z); hi[2] = t.x; lo[2] = t.y;
                t = split1(f0.w); hi[3] = t.x; lo[3] = t.y;
                t = split1(f1.x); hi[4] = t.x; lo[4] = t.y;
                t = split1(f1.y); hi[5] = t.x; lo[5] = t.y;
                t = split1(f1.z); hi[6] = t.x; lo[6] = t.y;
                t = split1(f1.w); hi[7] = t.x; lo[7] = t.y;
                wfh[kc] = hi; wfl[kc] = lo;
            }
        }
    }

    // ---- updater decode: all 512 threads, cell (layer ul, col ucc, batch ub) ----
    const int ul = tid >> 8, ub = (tid >> 4) & 15, ucc = tid & 15;
    const int ucol = rs * 16 + ucc;
    float ubias[4];
    {
        const float* bi = ul ? bih1 : bih0;
        const float* bh = ul ? bhh1 : bhh0;
        #pragma unroll
        for (int g = 0; g < 4; ++g) ubias[g] = bi[g * 256 + ucol] + bh[g * 256 + ucol];
    }
    float cst = 0.f, h1last = 0.f;

    // staging decode
    const int sn = tid >> 5, sk = (tid & 31) * 8;
    const int xn = tid >> 4, xd4 = (tid & 15) * 4;

    grid.sync();   // init visible device-wide

    float4 xpre;
    if (tid < 256)
        xpre = *(const float4*)&x[((size_t)(bbase + xn) * Tsz + 0) * 64 + xd4];

    for (int s = 0; s <= Tsz; ++s) {
        const int rp = (s + 1) & 1;   // parity of h0[s-1]
        const int rq = s & 1;         // parity of h1[s-2]

        // ---- wait for superstep s-1 of this bs-group (wave 0 only) ----
        if (s > 0) {
            if (w == 0) {
                if (rs == 0) {
                    // relay: tight-poll arrival line P, then publish epoch F
                    const unsigned* pp = &syn[bs * 256 + (lane & 15)];
                    while (!__all((int)(LOADX(pp) >= (unsigned)s))) { }
                    if (lane == 0)
                        STOREX(&syn[4096 + bs * 256], (unsigned)s);
                } else {
                    const unsigned* fp = &syn[4096 + bs * 256];
                    while (LOADX(fp) < (unsigned)s)
                        __builtin_amdgcn_s_sleep(1);
                }
            }
            __syncthreads();   // S0: release waves 1..7
        }

        // ---- stage h0[s-1], h1[s-2] (packed-uint load + v_perm unpack), x[s] ----
        {
            const unsigned* q0 = &h0u[((size_t)(rp * 256) + bbase + sn) * 256 + sk];
            const unsigned* q1 = &h1u[((size_t)(rq * 256) + bbase + sn) * 256 + sk];
            unsigned a[8], b[8];
            #pragma unroll
            for (int i = 0; i < 8; ++i) a[i] = LOADX(q0 + i);
            #pragma unroll
            for (int i = 0; i < 8; ++i) b[i] = LOADX(q1 + i);
            uint4 hi4, lo4;
            hi4.x = __builtin_amdgcn_perm(a[1], a[0], 0x07060302u);
            hi4.y = __builtin_amdgcn_perm(a[3], a[2], 0x07060302u);
            hi4.z = __builtin_amdgcn_perm(a[5], a[4], 0x07060302u);
            hi4.w = __builtin_amdgcn_perm(a[7], a[6], 0x07060302u);
            lo4.x = __builtin_amdgcn_perm(a[1], a[0], 0x05040100u);
            lo4.y = __builtin_amdgcn_perm(a[3], a[2], 0x05040100u);
            lo4.z = __builtin_amdgcn_perm(a[5], a[4], 0x05040100u);
            lo4.w = __builtin_amdgcn_perm(a[7], a[6], 0x05040100u);
            *(uint4*)&Bh[0][sn * PB0 + sk] = hi4;
            *(uint4*)&Bh[1][sn * PB0 + sk] = lo4;
            hi4.x = __builtin_amdgcn_perm(b[1], b[0], 0x07060302u);
            hi4.y = __builtin_amdgcn_perm(b[3], b[2], 0x07060302u);
            hi4.z = __builtin_amdgcn_perm(b[5], b[4], 0x07060302u);
            hi4.w = __builtin_amdgcn_perm(b[7], b[6], 0x07060302u);
            lo4.x = __builtin_amdgcn_perm(b[1], b[0], 0x05040100u);
            lo4.y = __builtin_amdgcn_perm(b[3], b[2], 0x05040100u);
            lo4.z = __builtin_amdgcn_perm(b[5], b[4], 0x05040100u);
            lo4.w = __builtin_amdgcn_perm(b[7], b[6], 0x05040100u);
            *(uint4*)&Bh[0][B1B + sn * PB1 + sk] = hi4;
            *(uint4*)&Bh[1][B1B + sn * PB1 + sk] = lo4;
        }
        if (s < Tsz && tid < 256) {
            float4 xv = xpre;
            short4v xh, xl; short2 t;
            t = split1(xv.x); xh[0] = t.x; xl[0] = t.y;
            t = split1(xv.y); xh[1] = t.x; xl[1] = t.y;
            t = split1(xv.z); xh[2] = t.x; xl[2] = t.y;
            t = split1(xv.w); xh[3] = t.x; xl[3] = t.y;
            *(short4v*)&Bh[0][xn * PB0 + 256 + xd4] = xh;
            *(short4v*)&Bh[1][xn * PB0 + 256 + xd4] = xl;
        }
        __syncthreads();   // S1: Bh staged

        // x prefetch for next superstep (drains naturally before use)
        if (tid < 256 && s + 1 < Tsz)
            xpre = *(const float4*)&x[((size_t)(bbase + xn) * Tsz + (s + 1)) * 64 + xd4];

        // ---- MFMA: full-K tile per wave, register A-frags, 3 independent
        //      accumulator chains (hi*hi / hi*lo / lo*hi) to cut dep latency ----
        float4v a0 = {0.f, 0.f, 0.f, 0.f};
        float4v a1 = {0.f, 0.f, 0.f, 0.f};
        float4v a2 = {0.f, 0.f, 0.f, 0.f};
        if (w < 4) {                         // L0: K=320 over h0|x
            #pragma unroll
            for (int kc = 0; kc < 10; ++kc) {
                const int bo = bBase0 + kc * 32;
                short8 bh2 = *(const short8*)&Bh[0][bo];
                short8 bl2 = *(const short8*)&Bh[1][bo];
                a0 = MFMA16(wfh[kc], bh2, a0);
                a1 = MFMA16(wfh[kc], bl2, a1);
                a2 = MFMA16(wfl[kc], bh2, a2);
            }
        } else {                             // L1: K=512 (h0 then h1)
            #pragma unroll
            for (int kc = 0; kc < 8; ++kc) {
                const int bo = bBase0 + kc * 32;
                short8 bh2 = *(const short8*)&Bh[0][bo];
                short8 bl2 = *(const short8*)&Bh[1][bo];
                a0 = MFMA16(wfh[kc], bh2, a0);
                a1 = MFMA16(wfh[kc], bl2, a1);
                a2 = MFMA16(wfl[kc], bh2, a2);
            }
            #pragma unroll
            for (int kc = 8; kc < 16; ++kc) {
                const int bo = bBase1 + (kc - 8) * 32;
                short8 bh2 = *(const short8*)&Bh[0][bo];
                short8 bl2 = *(const short8*)&Bh[1][bo];
                a0 = MFMA16(wfh[kc], bh2, a0);
                a1 = MFMA16(wfh[kc], bl2, a1);
                a2 = MFMA16(wfl[kc], bh2, a2);
            }
        }
        float4v acc = (a0 + a1) + a2;
        #pragma unroll
        for (int r = 0; r < 4; ++r)
            zf[w * 16 + quad * 4 + r][n16] = acc[r];
        __syncthreads();   // S2: zf complete

        // ---- cell update (all 512 threads own one cell) ----
        {
            const bool active = ul ? (s >= 1) : (s < Tsz);
            if (active) {
                const int mb = ul * 64 + ucc;
                float z0 = zf[mb +  0][ub] + ubias[0];
                float z1 = zf[mb + 16][ub] + ubias[1];
                float z2 = zf[mb + 32][ub] + ubias[2];
                float z3 = zf[mb + 48][ub] + ubias[3];
                float ii = sigm(z0), ff = sigm(z1);
                float gg = tanh_fast(z2), oo = sigm(z3);
                float c = ff * cst + ii * gg; cst = c;
                float hval = oo * tanh_fast(c);
                short2 hl = split1(hval);
                unsigned pk = ((unsigned)(unsigned short)hl.x << 16) |
                              (unsigned)(unsigned short)hl.y;
                if (ul) {
                    h1last = hval;
                    STOREX(&h1u[((size_t)(((s + 1) & 1) * 256) + bbase + ub) * 256 + ucol], pk);
                } else {
                    STOREX(&h0u[((size_t)((s & 1) * 256) + bbase + ub) * 256 + ucol], pk);
                }
            }
        }

        // ---- drain (S3: per-wave vmcnt(0) before barrier -> h stores done),
        //      then one parallel store to our own P word (read only by relay) ----
        __syncthreads();   // S3
        if (tid == 0)
            STOREX(&syn[bs * 256 + rs], (unsigned)(s + 1));
    }

    // ---- epilogue: out[b] += sum_cols h1_final * Wf ----
    if (ul == 1) {
        atomicAdd(&out[bbase + ub], h1last * Wf[ucol]);
    }
}

extern "C" void kernel_launch(void* const* d_in, const int* in_sizes, int n_in,
                              void* d_out, int out_size, void* d_ws, size_t ws_size,
                              hipStream_t stream) {
    const float* x    = (const float*)d_in[0];
    const float* Wih0 = (const float*)d_in[1];
    const float* Whh0 = (const float*)d_in[2];
    const float* bih0 = (const float*)d_in[3];
    const float* bhh0 = (const float*)d_in[4];
    const float* Wih1 = (const float*)d_in[5];
    const float* Whh1 = (const float*)d_in[6];
    const float* bih1 = (const float*)d_in[7];
    const float* bhh1 = (const float*)d_in[8];
    const float* Wf   = (const float*)d_in[9];
    const float* bf   = (const float*)d_in[10];
    float* out = (float*)d_out;
    float* ws  = (float*)d_ws;   // 1 MB packed h buffers + 32 KB sync area

    void* args[] = {
        (void*)&x, (void*)&Wih0, (void*)&Whh0, (void*)&bih0, (void*)&bhh0,
        (void*)&Wih1, (void*)&Whh1, (void*)&bih1, (void*)&bhh1,
        (void*)&Wf, (void*)&bf, (void*)&out, (void*)&ws
    };
    hipLaunchCooperativeKernel((void*)lstm2_mfma, dim3(NBLK), dim3(NTHR),
                               args, 0, stream);
}

// Round 7
// 3427.520 us; speedup vs baseline: 3.4464x; 1.0430x over previous
//
#include <hip/hip_runtime.h>
#include <hip/hip_cooperative_groups.h>
#include <math.h>

namespace cg = cooperative_groups;

#define Tsz 512
#define NBLK 256
#define NTHR 512

// LDS pitches (shorts): dword pitch ≡ 4 (mod 32), 16B-aligned — empirical optimum for
// the MFMA fragment b128 pattern (R5/R8: 2.4e8 conflicts; odd-dw: 4.4e8; ≡0: 1.1e9).
#define PB0 328   // B h0|x rows (320 used)  164 dw
#define PB1 264   // B h1 rows  (256 used)   132 dw
#define B1B 5248  // 16*PB0

// watchdog: ~650x the worst legitimate wait; converts any protocol stall into
// a terminating wrong-answer (diagnosable) instead of a GPU hang.
#define SPIN_GUARD (1 << 17)

typedef short short8  __attribute__((ext_vector_type(8)));
typedef short short4v __attribute__((ext_vector_type(4)));
typedef float float4v __attribute__((ext_vector_type(4)));

#define MFMA16(a, b, c) __builtin_amdgcn_mfma_f32_16x16x32_bf16((a), (b), (c), 0, 0, 0)
#define LOADX(p) __hip_atomic_load((p), __ATOMIC_RELAXED, __HIP_MEMORY_SCOPE_AGENT)
#define STOREX(p, v) __hip_atomic_store((p), (v), __ATOMIC_RELAXED, __HIP_MEMORY_SCOPE_AGENT)

__device__ __forceinline__ float sigm(float x) { return 1.0f / (1.0f + __expf(-x)); }
__device__ __forceinline__ float tanh_fast(float x) { return 2.0f / (1.0f + __expf(-2.0f * x)) - 1.0f; }

// fp32 -> bf16 hi (x) + bf16 lo (y), RNE both
__device__ __forceinline__ short2 split1(float f) {
    unsigned u = __float_as_uint(f);
    unsigned r = u + 0x7FFFu + ((u >> 16) & 1u);
    short h = (short)(r >> 16);
    float hf = __uint_as_float(r & 0xFFFF0000u);
    float d  = f - hf;
    unsigned u2 = __float_as_uint(d);
    unsigned r2 = u2 + 0x7FFFu + ((u2 >> 16) & 1u);
    return make_short2(h, (short)(r2 >> 16));
}

// Weight-stationary 2-layer LSTM, bf16-split-3 MFMA, ONE pass per superstep.
// 256 blocks = 16 row-slices (16 cols) x 16 batch-slices (16 batches).
// M=128 rows (L0 rows 0..63 = gate*16+col, L1 rows 64..127), N=16 batches.
// 8 waves = 8 16x16 tiles, FULL K per wave (L0: K=320 h0|x, L1: K=512 h0|h1).
//
// Sync (R7): R3-proven ordering skeleton (data stores -> S3 drain -> one
// relaxed flag store per block; consumers poll then load; NO fences, NO RMW
// chain), but each block's flag lives on its OWN 64B cacheline:
//   flag(bs,rs) = syn[(bs*16+rs)*16]
// This removes the single-line false sharing that serialized every previous
// variant (baseline: 16 RMWs on one word; R1/R3: 16 stores packed in one
// line + poll flood stealing the line). Publishes are now 16 parallel
// writes to 16 distinct lines; the poll is one 16-lane gather across them.
__global__ __launch_bounds__(NTHR, 1)
void lstm2_mfma(const float* __restrict__ x,
                const float* __restrict__ Wih0, const float* __restrict__ Whh0,
                const float* __restrict__ bih0, const float* __restrict__ bhh0,
                const float* __restrict__ Wih1, const float* __restrict__ Whh1,
                const float* __restrict__ bih1, const float* __restrict__ bhh1,
                const float* __restrict__ Wf,   const float* __restrict__ bf,
                float* __restrict__ out, float* __restrict__ ws)
{
    cg::grid_group grid = cg::this_grid();
    const int tid = threadIdx.x;
    const int rs  = blockIdx.x >> 4;   // row-slice: cols [rs*16, rs*16+16)
    const int bs  = blockIdx.x & 15;   // batch-slice: batches [bs*16, bs*16+16)
    const int bbase = bs * 16;

    __shared__ short Bh[2][9472];      // 37.9 KB (h0|x: 16*PB0, h1: 16*PB1)
    __shared__ float zf[128][17];      // 8.7 KB

    unsigned* h0u = (unsigned*)ws;             // [2 parity][256 batch][256 col] packed
    unsigned* h1u = (unsigned*)ws + 2 * 256 * 256;
    unsigned* syn = (unsigned*)ws + 4 * 256 * 256;
    // flag(bs,rs) = syn[(bs*16+rs)*16] -> 256 flags, one 64B line each, 16KB

    // ---- init ----
    for (int i = blockIdx.x * NTHR + tid; i < 4 * 256 * 256; i += NBLK * NTHR)
        ((unsigned*)ws)[i] = 0u;
    if (tid == 0) STOREX(&syn[(bs * 16 + rs) * 16], 0u);
    if (rs == 0 && tid < 16) out[bbase + tid] = bf[0];

    // ---- mfma lane decode ----
    const int w = tid >> 6, lane = tid & 63;
    const int quad = lane >> 4, n16 = lane & 15;
    const int bBase0 = n16 * PB0 + quad * 8;
    const int bBase1 = B1B + n16 * PB1 + quad * 8;

    // ---- weight A-fragments -> registers (full K per wave) ----
    // Wave w<4: L0 tile rows w*16..+16 (within-layer row r = w*16+n16).
    // Wave w>=4: L1 tile rows (w-4)*16..+16.
    short8 wfh[16], wfl[16];
    {
        const int r = (w & 3) * 16 + n16;            // within-layer row 0..63
        const int g = r >> 4, cc = r & 15;
        const size_t grow = (size_t)(g * 256 + rs * 16 + cc);
        const int nkc = (w < 4) ? 10 : 16;
        #pragma unroll
        for (int kc = 0; kc < 16; ++kc) {
            if (kc < nkc) {
                const int k = kc * 32 + quad * 8;
                const float* src;
                if (w < 4)                           // L0: k<256 -> Whh0, else Wih0
                    src = (k < 256) ? &Whh0[grow * 256 + k] : &Wih0[grow * 64 + (k - 256)];
                else                                 // L1: k<256 -> Wih1 (vs h0), else Whh1 (vs h1)
                    src = (k < 256) ? &Wih1[grow * 256 + k] : &Whh1[grow * 256 + (k - 256)];
                float4 f0 = *(const float4*)src;
                float4 f1 = *(const float4*)(src + 4);
                short8 hi, lo; short2 t;
                t = split1(f0.x); hi[0] = t.x; lo[0] = t.y;
                t = split1(f0.y); hi[1] = t.x; lo[1] = t.y;
                t = split1(f0.z); hi[2] = t.x; lo[2] = t.y;
                t = split1(f0.w); hi[3] = t.x; lo[3] = t.y;
                t = split1(f1.x); hi[4] = t.x; lo[4] = t.y;
                t = split1(f1.y); hi[5] = t.x; lo[5] = t.y;
                t = split1(f1.z); hi[6] = t.x; lo[6] = t.y;
                t = split1(f1.w); hi[7] = t.x; lo[7] = t.y;
                wfh[kc] = hi; wfl[kc] = lo;
            }
        }
    }

    // ---- updater decode: all 512 threads, cell (layer ul, col ucc, batch ub) ----
    const int ul = tid >> 8, ub = (tid >> 4) & 15, ucc = tid & 15;
    const int ucol = rs * 16 + ucc;
    float ubias[4];
    {
        const float* bi = ul ? bih1 : bih0;
        const float* bh = ul ? bhh1 : bhh0;
        #pragma unroll
        for (int g = 0; g < 4; ++g) ubias[g] = bi[g * 256 + ucol] + bh[g * 256 + ucol];
    }
    float cst = 0.f, h1last = 0.f;

    // staging decode
    const int sn = tid >> 5, sk = (tid & 31) * 8;
    const int xn = tid >> 4, xd4 = (tid & 15) * 4;

    grid.sync();   // init visible device-wide

    float4 xpre;
    if (tid < 256)
        xpre = *(const float4*)&x[((size_t)(bbase + xn) * Tsz + 0) * 64 + xd4];

    for (int s = 0; s <= Tsz; ++s) {
        const int rp = (s + 1) & 1;   // parity of h0[s-1]
        const int rq = s & 1;         // parity of h1[s-2]

        // ---- wait for superstep s-1 of this bs-group: 16-lane gather poll
        //      across 16 DISTINCT cachelines (read-shared, no line stealing) ----
        if (s > 0) {
            const unsigned* fl = &syn[(bs * 16 + (lane & 15)) * 16];
            int guard = 0;
            while (!__all((int)(LOADX(fl) >= (unsigned)s))) {
                if (++guard > SPIN_GUARD) break;   // watchdog: fail, don't hang
                __builtin_amdgcn_s_sleep(1);
            }
        }

        // ---- stage h0[s-1], h1[s-2] (packed-uint load + v_perm unpack), x[s] ----
        {
            const unsigned* q0 = &h0u[((size_t)(rp * 256) + bbase + sn) * 256 + sk];
            const unsigned* q1 = &h1u[((size_t)(rq * 256) + bbase + sn) * 256 + sk];
            unsigned a[8], b[8];
            #pragma unroll
            for (int i = 0; i < 8; ++i) a[i] = LOADX(q0 + i);
            #pragma unroll
            for (int i = 0; i < 8; ++i) b[i] = LOADX(q1 + i);
            uint4 hi4, lo4;
            hi4.x = __builtin_amdgcn_perm(a[1], a[0], 0x07060302u);
            hi4.y = __builtin_amdgcn_perm(a[3], a[2], 0x07060302u);
            hi4.z = __builtin_amdgcn_perm(a[5], a[4], 0x07060302u);
            hi4.w = __builtin_amdgcn_perm(a[7], a[6], 0x07060302u);
            lo4.x = __builtin_amdgcn_perm(a[1], a[0], 0x05040100u);
            lo4.y = __builtin_amdgcn_perm(a[3], a[2], 0x05040100u);
            lo4.z = __builtin_amdgcn_perm(a[5], a[4], 0x05040100u);
            lo4.w = __builtin_amdgcn_perm(a[7], a[6], 0x05040100u);
            *(uint4*)&Bh[0][sn * PB0 + sk] = hi4;
            *(uint4*)&Bh[1][sn * PB0 + sk] = lo4;
            hi4.x = __builtin_amdgcn_perm(b[1], b[0], 0x07060302u);
            hi4.y = __builtin_amdgcn_perm(b[3], b[2], 0x07060302u);
            hi4.z = __builtin_amdgcn_perm(b[5], b[4], 0x07060302u);
            hi4.w = __builtin_amdgcn_perm(b[7], b[6], 0x07060302u);
            lo4.x = __builtin_amdgcn_perm(b[1], b[0], 0x05040100u);
            lo4.y = __builtin_amdgcn_perm(b[3], b[2], 0x05040100u);
            lo4.z = __builtin_amdgcn_perm(b[5], b[4], 0x05040100u);
            lo4.w = __builtin_amdgcn_perm(b[7], b[6], 0x05040100u);
            *(uint4*)&Bh[0][B1B + sn * PB1 + sk] = hi4;
            *(uint4*)&Bh[1][B1B + sn * PB1 + sk] = lo4;
        }
        if (s < Tsz && tid < 256) {
            float4 xv = xpre;
            short4v xh, xl; short2 t;
            t = split1(xv.x); xh[0] = t.x; xl[0] = t.y;
            t = split1(xv.y); xh[1] = t.x; xl[1] = t.y;
            t = split1(xv.z); xh[2] = t.x; xl[2] = t.y;
            t = split1(xv.w); xh[3] = t.x; xl[3] = t.y;
            *(short4v*)&Bh[0][xn * PB0 + 256 + xd4] = xh;
            *(short4v*)&Bh[1][xn * PB0 + 256 + xd4] = xl;
        }
        __syncthreads();   // S1: Bh staged

        // x prefetch for next superstep (drains naturally before use)
        if (tid < 256 && s + 1 < Tsz)
            xpre = *(const float4*)&x[((size_t)(bbase + xn) * Tsz + (s + 1)) * 64 + xd4];

        // ---- MFMA: full-K tile per wave, register A-frags, 3 independent
        //      accumulator chains (hi*hi / hi*lo / lo*hi) ----
        float4v a0 = {0.f, 0.f, 0.f, 0.f};
        float4v a1 = {0.f, 0.f, 0.f, 0.f};
        float4v a2 = {0.f, 0.f, 0.f, 0.f};
        if (w < 4) {                         // L0: K=320 over h0|x
            #pragma unroll
            for (int kc = 0; kc < 10; ++kc) {
                const int bo = bBase0 + kc * 32;
                short8 bh2 = *(const short8*)&Bh[0][bo];
                short8 bl2 = *(const short8*)&Bh[1][bo];
                a0 = MFMA16(wfh[kc], bh2, a0);
                a1 = MFMA16(wfh[kc], bl2, a1);
                a2 = MFMA16(wfl[kc], bh2, a2);
            }
        } else {                             // L1: K=512 (h0 then h1)
            #pragma unroll
            for (int kc = 0; kc < 8; ++kc) {
                const int bo = bBase0 + kc * 32;
                short8 bh2 = *(const short8*)&Bh[0][bo];
                short8 bl2 = *(const short8*)&Bh[1][bo];
                a0 = MFMA16(wfh[kc], bh2, a0);
                a1 = MFMA16(wfh[kc], bl2, a1);
                a2 = MFMA16(wfl[kc], bh2, a2);
            }
            #pragma unroll
            for (int kc = 8; kc < 16; ++kc) {
                const int bo = bBase1 + (kc - 8) * 32;
                short8 bh2 = *(const short8*)&Bh[0][bo];
                short8 bl2 = *(const short8*)&Bh[1][bo];
                a0 = MFMA16(wfh[kc], bh2, a0);
                a1 = MFMA16(wfh[kc], bl2, a1);
                a2 = MFMA16(wfl[kc], bh2, a2);
            }
        }
        float4v acc = (a0 + a1) + a2;
        #pragma unroll
        for (int r = 0; r < 4; ++r)
            zf[w * 16 + quad * 4 + r][n16] = acc[r];
        __syncthreads();   // S2: zf complete

        // ---- cell update (all 512 threads own one cell) ----
        {
            const bool active = ul ? (s >= 1) : (s < Tsz);
            if (active) {
                const int mb = ul * 64 + ucc;
                float z0 = zf[mb +  0][ub] + ubias[0];
                float z1 = zf[mb + 16][ub] + ubias[1];
                float z2 = zf[mb + 32][ub] + ubias[2];
                float z3 = zf[mb + 48][ub] + ubias[3];
                float ii = sigm(z0), ff = sigm(z1);
                float gg = tanh_fast(z2), oo = sigm(z3);
                float c = ff * cst + ii * gg; cst = c;
                float hval = oo * tanh_fast(c);
                short2 hl = split1(hval);
                unsigned pk = ((unsigned)(unsigned short)hl.x << 16) |
                              (unsigned)(unsigned short)hl.y;
                if (ul) {
                    h1last = hval;
                    STOREX(&h1u[((size_t)(((s + 1) & 1) * 256) + bbase + ub) * 256 + ucol], pk);
                } else {
                    STOREX(&h0u[((size_t)((s & 1) * 256) + bbase + ub) * 256 + ucol], pk);
                }
            }
        }

        // ---- drain (S3: per-wave vmcnt(0) before barrier -> h stores done),
        //      then one parallel store to our OWN flag line ----
        __syncthreads();   // S3
        if (tid == 0)
            STOREX(&syn[(bs * 16 + rs) * 16], (unsigned)(s + 1));
    }

    // ---- epilogue: out[b] += sum_cols h1_final * Wf ----
    if (ul == 1) {
        atomicAdd(&out[bbase + ub], h1last * Wf[ucol]);
    }
}

extern "C" void kernel_launch(void* const* d_in, const int* in_sizes, int n_in,
                              void* d_out, int out_size, void* d_ws, size_t ws_size,
                              hipStream_t stream) {
    const float* x    = (const float*)d_in[0];
    const float* Wih0 = (const float*)d_in[1];
    const float* Whh0 = (const float*)d_in[2];
    const float* bih0 = (const float*)d_in[3];
    const float* bhh0 = (const float*)d_in[4];
    const float* Wih1 = (const float*)d_in[5];
    const float* Whh1 = (const float*)d_in[6];
    const float* bih1 = (const float*)d_in[7];
    const float* bhh1 = (const float*)d_in[8];
    const float* Wf   = (const float*)d_in[9];
    const float* bf   = (const float*)d_in[10];
    float* out = (float*)d_out;
    float* ws  = (float*)d_ws;   // 1 MB packed h buffers + 16 KB flag area

    void* args[] = {
        (void*)&x, (void*)&Wih0, (void*)&Whh0, (void*)&bih0, (void*)&bhh0,
        (void*)&Wih1, (void*)&Whh1, (void*)&bih1, (void*)&bhh1,
        (void*)&Wf, (void*)&bf, (void*)&out, (void*)&ws
    };
    hipLaunchCooperativeKernel((void*)lstm2_mfma, dim3(NBLK), dim3(NTHR),
                               args, 0, stream);
}